// Round 9
// baseline (350.098 us; speedup 1.0000x reference)
//
#include <hip/hip_runtime.h>
#include <math.h>

#define NU_F 0.0031830988618379067f
#define HS 136   // halves per H row: 17*8 -> 16B-aligned, odd 16B-stride = bank-balanced

typedef __attribute__((ext_vector_type(8))) _Float16 half8;
typedef __attribute__((ext_vector_type(16))) float f32x16;

__device__ __forceinline__ float fast_tanh(float x) {
    const float e = __expf(2.f * x);
    return 1.f - 2.f / (e + 1.f);
}

// ---------------------------------------------------------------------------
// Weight prep: W[l][k][n] fp32 -> k-tiled fp16 hi/lo:
//   idx = l*16384 + (k>>4)*2048 + n*16 + (k&15)
// The hi stream is contiguous in g = l*8 + kt (stride 2048): one flat
// prefetch sequence across all 3 layers. lo stream at +49152.
// ---------------------------------------------------------------------------
__global__ void prep_kernel(const float* __restrict__ W1,
                            const float* __restrict__ W2,
                            const float* __restrict__ W3,
                            _Float16* __restrict__ ws)
{
    const int g = blockIdx.x * 256 + threadIdx.x;   // 0..49151
    const int l = g >> 14;
    const int r = g & 16383;
    const int n = r & 127;
    const int k = r >> 7;
    const float* W = (l == 0) ? W1 : (l == 1) ? W2 : W3;
    const float w = W[k * 128 + n];
    const _Float16 hi = (_Float16)w;
    const _Float16 lo = (_Float16)(w - (float)hi);
    const int idx = l * 16384 + (k >> 4) * 2048 + n * 16 + (k & 15);
    ws[idx]         = hi;
    ws[49152 + idx] = lo;
}

// ---------------------------------------------------------------------------
// One hidden layer: K-loop (2-term split-fp16 MFMA, W fp32-exact) fed by the
// flat cross-layer B queue (depth 3), then register epilogue + in-place H.
// g = 8*L + kt is compile-time after unroll -> queue indices stay in regs.
// ---------------------------------------------------------------------------
template<int L, bool IS_EQ>
__device__ __forceinline__ void layer_run(const _Float16* __restrict__ qh_base,
                                          const _Float16* __restrict__ ql_base,
                                          half8 (&qh)[3], half8 (&ql)[3],
                                          _Float16 (*Hh)[HS],
                                          float bias, int col, int khalf, int ncol)
{
    f32x16 acc[2];
    #pragma unroll
    for (int mt = 0; mt < 2; ++mt)
        #pragma unroll
        for (int e = 0; e < 16; ++e) acc[mt][e] = 0.f;

    #pragma unroll
    for (int kt = 0; kt < 8; ++kt) {
        const int g = 8 * L + kt;
        half8 nh, nl;
        if (g + 3 < 24) {
            nh = *(const half8*)(qh_base + (g + 3) * 2048);
            nl = *(const half8*)(ql_base + (g + 3) * 2048);
        }
        const int k0 = kt * 16 + khalf * 8;
        #pragma unroll
        for (int mt = 0; mt < 2; ++mt) {
            const half8 ah = *(const half8*)&Hh[mt * 32 + col][k0];
            acc[mt] = __builtin_amdgcn_mfma_f32_32x32x16_f16(ah, ql[g % 3], acc[mt], 0, 0, 0);
            acc[mt] = __builtin_amdgcn_mfma_f32_32x32x16_f16(ah, qh[g % 3], acc[mt], 0, 0, 0);
        }
        if (g + 3 < 24) { qh[g % 3] = nh; ql[g % 3] = nl; }
    }
    __syncthreads();   // all reads of H done -> in-place overwrite safe

    // epilogue: reg group 4g..4g+3 = rows mt*32 + 8g + 4*khalf + {0..3};
    // eq: rows = {u,ut,ux,uxx} of one point -> chain rule in registers.
    #pragma unroll
    for (int mt = 0; mt < 2; ++mt)
        #pragma unroll
        for (int gg = 0; gg < 4; ++gg) {
            const int mrow0 = mt * 32 + 8 * gg + 4 * khalf;
            const float A0 = acc[mt][4 * gg + 0];
            const float A1 = acc[mt][4 * gg + 1];
            const float A2 = acc[mt][4 * gg + 2];
            const float A3 = acc[mt][4 * gg + 3];
            float h[4];
            if (IS_EQ) {
                const float a = fast_tanh(A0 + bias);
                const float s = 1.f - a * a;
                h[0] = a;
                h[1] = s * A1;
                h[2] = s * A2;
                h[3] = fmaf(s, A3, -2.f * a * s * A2 * A2);
            } else {
                h[0] = fast_tanh(A0 + bias);
                h[1] = fast_tanh(A1 + bias);
                h[2] = fast_tanh(A2 + bias);
                h[3] = fast_tanh(A3 + bias);
            }
            #pragma unroll
            for (int c = 0; c < 4; ++c)
                Hh[mrow0 + c][ncol] = (_Float16)h[c];
        }
    __syncthreads();
}

// ---------------------------------------------------------------------------
// Blocks 0..8191: equation, 16 pts (M=64 rows, m = 4p + channel).
// Blocks 8192..8319: init/bound forward-only, 64 pts (m = p).
// Wave w computes cols [32w,32w+32) for all 64 rows.
// ---------------------------------------------------------------------------
__launch_bounds__(256, 8)
__global__ void pinn_kernel(const float* __restrict__ tx_eq,
                            const float* __restrict__ tx_init,
                            const float* __restrict__ tx_bnd,
                            const float* __restrict__ W0, const float* __restrict__ b0,
                            const float* __restrict__ b1, const float* __restrict__ b2,
                            const float* __restrict__ b3,
                            const float* __restrict__ W4, const float* __restrict__ b4,
                            const _Float16* __restrict__ wt,
                            float* __restrict__ out)
{
    __shared__ _Float16 Hh[64][HS];   // 17.4 KB, in-place across layers

    const int tid   = threadIdx.x;
    const int blk   = blockIdx.x;
    const bool is_eq = (blk < 8192);
    const int w     = tid >> 6;
    const int lane  = tid & 63;
    const int col   = lane & 31;
    const int khalf = lane >> 5;
    const int ncol  = 32 * w + col;

    // prime the flat B queue (g = 0,1,2) before input-layer compute so the
    // loads' L2 latency is hidden behind the input tanh work.
    const int wofs = ncol * 16 + khalf * 8;
    const _Float16* __restrict__ qh_base = wt + wofs;
    const _Float16* __restrict__ ql_base = wt + 49152 + wofs;
    half8 qh[3], ql[3];
    qh[0] = *(const half8*)(qh_base);          ql[0] = *(const half8*)(ql_base);
    qh[1] = *(const half8*)(qh_base + 2048);   ql[1] = *(const half8*)(ql_base + 2048);
    qh[2] = *(const half8*)(qh_base + 4096);   ql[2] = *(const half8*)(ql_base + 4096);

    const float biasv0 = b1[ncol];
    const float biasv1 = b2[ncol];
    const float biasv2 = b3[ncol];

    // ---- input layer (K=2, pointwise, fp32) ----
    if (is_eq) {
        const int p  = tid >> 4;                 // 0..15
        const int f0 = (tid & 15) * 8;
        const float tv = tx_eq[blk * 32 + 2 * p];
        const float xv = tx_eq[blk * 32 + 2 * p + 1];
        float vch[4][8];
        #pragma unroll
        for (int j = 0; j < 8; ++j) {
            const int f = f0 + j;
            const float w0v = W0[f];             // dz/dt
            const float w1v = W0[128 + f];       // dz/dx
            const float z = fmaf(tv, w0v, fmaf(xv, w1v, b0[f]));
            const float a = fast_tanh(z);
            const float s = 1.f - a * a;
            vch[0][j] = a;
            vch[1][j] = s * w0v;
            vch[2][j] = s * w1v;
            vch[3][j] = -2.f * a * s * w1v * w1v;
        }
        const int m0 = 4 * p;
        #pragma unroll
        for (int c = 0; c < 4; ++c) {
            half8 hh;
            #pragma unroll
            for (int j = 0; j < 8; ++j) hh[j] = (_Float16)vch[c][j];
            *(half8*)&Hh[m0 + c][f0] = hh;
        }
    } else {
        const int p  = tid >> 2;                 // 0..63 == row m
        const int f0 = (tid & 3) * 32;
        const int gp = (blk - 8192) * 64 + p;
        const float* src = (gp < 4096) ? tx_init : tx_bnd;
        const int idx = (gp < 4096) ? gp : gp - 4096;
        const float tv = src[2 * idx];
        const float xv = src[2 * idx + 1];
        #pragma unroll
        for (int g = 0; g < 4; ++g) {
            half8 hh;
            #pragma unroll
            for (int j = 0; j < 8; ++j) {
                const int f = f0 + 8 * g + j;
                hh[j] = (_Float16)fast_tanh(fmaf(tv, W0[f], fmaf(xv, W0[128 + f], b0[f])));
            }
            *(half8*)&Hh[p][f0 + 8 * g] = hh;
        }
    }
    __syncthreads();

    if (is_eq) {
        layer_run<0, true >(qh_base, ql_base, qh, ql, Hh, biasv0, col, khalf, ncol);
        layer_run<1, true >(qh_base, ql_base, qh, ql, Hh, biasv1, col, khalf, ncol);
        layer_run<2, true >(qh_base, ql_base, qh, ql, Hh, biasv2, col, khalf, ncol);
    } else {
        layer_run<0, false>(qh_base, ql_base, qh, ql, Hh, biasv0, col, khalf, ncol);
        layer_run<1, false>(qh_base, ql_base, qh, ql, Hh, biasv1, col, khalf, ncol);
        layer_run<2, false>(qh_base, ql_base, qh, ql, Hh, biasv2, col, khalf, ncol);
    }

    // ---- final layer (128 -> 1): thread t reduces k-quarter (t&3) of row t>>2
    {
        const float b4v = b4[0];
        const int m = tid >> 2;
        const int q = tid & 3;
        float dot = 0.f;
        #pragma unroll
        for (int g = 0; g < 4; ++g) {
            const int f = 32 * q + 8 * g;
            const half8 hh = *(const half8*)&Hh[m][f];
            const float4 wa = *(const float4*)&W4[f];
            const float4 wb = *(const float4*)&W4[f + 4];
            dot = fmaf((float)hh[0], wa.x, dot);
            dot = fmaf((float)hh[1], wa.y, dot);
            dot = fmaf((float)hh[2], wa.z, dot);
            dot = fmaf((float)hh[3], wa.w, dot);
            dot = fmaf((float)hh[4], wb.x, dot);
            dot = fmaf((float)hh[5], wb.y, dot);
            dot = fmaf((float)hh[6], wb.z, dot);
            dot = fmaf((float)hh[7], wb.w, dot);
        }
        dot += __shfl_xor(dot, 1);   // reduce across the 4 k-quarters
        dot += __shfl_xor(dot, 2);   // full row-dot at all 4 lanes of the row

        if (is_eq) {
            // wave w holds rows [16w,16w+16) = points [4w,4w+4); lane = 16p' + 4c + q
            const float uu   = __shfl(dot, (lane & 48) + 0)  + b4v;
            const float utv  = __shfl(dot, (lane & 48) + 4);
            const float uxv  = __shfl(dot, (lane & 48) + 8);
            const float uxxv = __shfl(dot, (lane & 48) + 12);
            if ((lane & 15) == 0)
                out[blk * 16 + 4 * w + (lane >> 4)] = fmaf(uu, uxv, utv) - NU_F * uxxv;
        } else {
            if (q == 0)
                out[131072 + (blk - 8192) * 64 + m] = dot + b4v;
        }
    }
}

extern "C" void kernel_launch(void* const* d_in, const int* in_sizes, int n_in,
                              void* d_out, int out_size, void* d_ws, size_t ws_size,
                              hipStream_t stream)
{
    const float* tx_eq   = (const float*)d_in[0];
    const float* tx_init = (const float*)d_in[1];
    const float* tx_bnd  = (const float*)d_in[2];
    const float* W0 = (const float*)d_in[3];
    const float* b0 = (const float*)d_in[4];
    const float* W1 = (const float*)d_in[5];
    const float* b1 = (const float*)d_in[6];
    const float* W2 = (const float*)d_in[7];
    const float* b2 = (const float*)d_in[8];
    const float* W3 = (const float*)d_in[9];
    const float* b3 = (const float*)d_in[10];
    const float* W4 = (const float*)d_in[11];
    const float* b4 = (const float*)d_in[12];
    float* out = (float*)d_out;
    _Float16* wt = (_Float16*)d_ws;   // needs 196608 B

    hipLaunchKernelGGL(prep_kernel, dim3(192), dim3(256), 0, stream, W1, W2, W3, wt);
    // 8192 eq blocks (16 pts) + 128 ib blocks (64 pts)
    hipLaunchKernelGGL(pinn_kernel, dim3(8320), dim3(256), 0, stream,
                       tx_eq, tx_init, tx_bnd, W0, b0, b1, b2, b3, W4, b4,
                       (const _Float16*)wt, out);
}

// Round 10
// 219.279 us; speedup vs baseline: 1.5966x; 1.5966x over previous
//
#include <hip/hip_runtime.h>
#include <math.h>

#define NU_F 0.0031830988618379067f
#define HS 136   // halves per H row: 17*8 -> 16B-aligned, odd 16B-stride = bank-balanced

typedef __attribute__((ext_vector_type(8))) _Float16 half8;
typedef __attribute__((ext_vector_type(16))) float f32x16;

// tanh via exp2 + fast rcp: ~5 VALU (2 on trans pipe). inf-safe: e=inf -> 1, e=0 -> -1.
__device__ __forceinline__ float fast_tanh(float x) {
    const float e = __builtin_amdgcn_exp2f(x * 2.8853900817779268f);  // e^(2x)
    const float r = __builtin_amdgcn_rcpf(e + 1.f);
    return fmaf(-2.f, r, 1.f);
}

// ---------------------------------------------------------------------------
// Weight prep: W[l][k][n] fp32 -> k-tiled fp16 hi/lo:
//   idx = l*16384 + (k>>4)*2048 + n*16 + (k&15)
// so a wave's per-kt B-read (n-contiguous, 16 halves each) is one 1KB block.
// B keeps the hi+lo split (W at fp32 accuracy); A (activations) is fp16-only.
// ---------------------------------------------------------------------------
__global__ void prep_kernel(const float* __restrict__ W1,
                            const float* __restrict__ W2,
                            const float* __restrict__ W3,
                            _Float16* __restrict__ ws)
{
    const int g = blockIdx.x * 256 + threadIdx.x;   // 0..49151
    const int l = g >> 14;
    const int r = g & 16383;
    const int n = r & 127;
    const int k = r >> 7;
    const float* W = (l == 0) ? W1 : (l == 1) ? W2 : W3;
    const float w = W[k * 128 + n];
    const _Float16 hi = (_Float16)w;
    const _Float16 lo = (_Float16)(w - (float)hi);
    const int idx = l * 16384 + (k >> 4) * 2048 + n * 16 + (k & 15);
    ws[idx]         = hi;
    ws[49152 + idx] = lo;
}

// ---------------------------------------------------------------------------
// Blocks 0..8191: equation, 16 pts (M=64 rows, m = 4p + channel).
// Blocks 8192..8319: init/bound forward-only, 64 pts (m = p).
// Wave w computes cols [32w,32w+32) for all 64 rows (mt=0,1).
// Per (kt,mt): 2 MFMAs (ah*bl + ah*bh) -> W fp32-exact, activations fp16.
// H single fp16 buffer (17.4 KB) -> 8 blocks/CU; B-head of the next layer is
// prefetched before each epilogue so no layer starts with a cold L2 load.
// ---------------------------------------------------------------------------
__launch_bounds__(256, 8)
__global__ void pinn_kernel(const float* __restrict__ tx_eq,
                            const float* __restrict__ tx_init,
                            const float* __restrict__ tx_bnd,
                            const float* __restrict__ W0, const float* __restrict__ b0,
                            const float* __restrict__ b1, const float* __restrict__ b2,
                            const float* __restrict__ b3,
                            const float* __restrict__ W4, const float* __restrict__ b4,
                            const _Float16* __restrict__ wt,
                            float* __restrict__ out)
{
    __shared__ _Float16 Hh[64][HS];   // 17.4 KB, in-place across layers

    const int tid   = threadIdx.x;
    const int blk   = blockIdx.x;
    const bool is_eq = (blk < 8192);
    const int w     = tid >> 6;
    const int lane  = tid & 63;
    const int col   = lane & 31;
    const int khalf = lane >> 5;
    const int ncol  = 32 * w + col;

    // B queue registers live in kernel scope (R8-proven codegen: no scratch).
    const int wofs = ncol * 16 + khalf * 8;
    half8 bh[2], bl[2];
    {   // prime layer 0's head; latency hidden behind input-layer tanh work
        const _Float16* ph = wt + wofs;
        const _Float16* pl = ph + 49152;
        bh[0] = *(const half8*)(ph);         bl[0] = *(const half8*)(pl);
        bh[1] = *(const half8*)(ph + 2048);  bl[1] = *(const half8*)(pl + 2048);
    }

    // ---- input layer (K=2, pointwise, fp32) ----
    if (is_eq) {
        const int p  = tid >> 4;                 // 0..15
        const int f0 = (tid & 15) * 8;
        const float tv = tx_eq[blk * 32 + 2 * p];
        const float xv = tx_eq[blk * 32 + 2 * p + 1];
        float vch[4][8];
        #pragma unroll
        for (int j = 0; j < 8; ++j) {
            const int f = f0 + j;
            const float w0v = W0[f];             // dz/dt
            const float w1v = W0[128 + f];       // dz/dx
            const float z = fmaf(tv, w0v, fmaf(xv, w1v, b0[f]));
            const float a = fast_tanh(z);
            const float s = 1.f - a * a;
            vch[0][j] = a;
            vch[1][j] = s * w0v;
            vch[2][j] = s * w1v;
            vch[3][j] = -2.f * a * s * w1v * w1v;
        }
        const int m0 = 4 * p;
        #pragma unroll
        for (int c = 0; c < 4; ++c) {
            half8 hh;
            #pragma unroll
            for (int j = 0; j < 8; ++j) hh[j] = (_Float16)vch[c][j];
            *(half8*)&Hh[m0 + c][f0] = hh;
        }
    } else {
        const int p  = tid >> 2;                 // 0..63 == row m
        const int f0 = (tid & 3) * 32;
        const int gp = (blk - 8192) * 64 + p;
        const float* src = (gp < 4096) ? tx_init : tx_bnd;
        const int idx = (gp < 4096) ? gp : gp - 4096;
        const float tv = src[2 * idx];
        const float xv = src[2 * idx + 1];
        #pragma unroll
        for (int g = 0; g < 4; ++g) {
            half8 hh;
            #pragma unroll
            for (int j = 0; j < 8; ++j) {
                const int f = f0 + 8 * g + j;
                hh[j] = (_Float16)fast_tanh(fmaf(tv, W0[f], fmaf(xv, W0[128 + f], b0[f])));
            }
            *(half8*)&Hh[p][f0 + 8 * g] = hh;
        }
    }
    __syncthreads();

    const float* barr[3] = {b1, b2, b3};

    #pragma unroll 1
    for (int layer = 0; layer < 3; ++layer) {
        const _Float16* __restrict__ ph = wt + layer * 16384 + wofs;
        const _Float16* __restrict__ pl = ph + 49152;
        const float bias = barr[layer][ncol];

        f32x16 acc[2];
        #pragma unroll
        for (int mt = 0; mt < 2; ++mt)
            #pragma unroll
            for (int e = 0; e < 16; ++e) acc[mt][e] = 0.f;

        // K-loop: rolling distance-2 B prefetch (each load = coalesced 1KB/wave)
        #pragma unroll
        for (int kt = 0; kt < 8; ++kt) {
            half8 nbh, nbl;
            if (kt < 6) {
                nbh = *(const half8*)(ph + (kt + 2) * 2048);
                nbl = *(const half8*)(pl + (kt + 2) * 2048);
            }
            const int k0 = kt * 16 + khalf * 8;
            #pragma unroll
            for (int mt = 0; mt < 2; ++mt) {
                const half8 ah = *(const half8*)&Hh[mt * 32 + col][k0];
                acc[mt] = __builtin_amdgcn_mfma_f32_32x32x16_f16(ah, bl[kt & 1], acc[mt], 0, 0, 0);
                acc[mt] = __builtin_amdgcn_mfma_f32_32x32x16_f16(ah, bh[kt & 1], acc[mt], 0, 0, 0);
            }
            if (kt < 6) { bh[kt & 1] = nbh; bl[kt & 1] = nbl; }
        }

        // prefetch NEXT layer's head chunks now: the epilogue below hides the
        // L2 latency, so the next K-loop starts warm.
        if (layer < 2) {
            const _Float16* ph2 = ph + 16384;
            const _Float16* pl2 = pl + 16384;
            bh[0] = *(const half8*)(ph2);         bl[0] = *(const half8*)(pl2);
            bh[1] = *(const half8*)(ph2 + 2048);  bl[1] = *(const half8*)(pl2 + 2048);
        }
        __syncthreads();   // all reads of H done -> in-place overwrite safe

        // epilogue: reg group 4g..4g+3 = rows mt*32 + 8g + 4*khalf + {0..3};
        // eq: rows = {u,ut,ux,uxx} of one point -> chain rule in registers.
        #pragma unroll
        for (int mt = 0; mt < 2; ++mt)
            #pragma unroll
            for (int g = 0; g < 4; ++g) {
                const int mrow0 = mt * 32 + 8 * g + 4 * khalf;
                const float A0 = acc[mt][4 * g + 0];
                const float A1 = acc[mt][4 * g + 1];
                const float A2 = acc[mt][4 * g + 2];
                const float A3 = acc[mt][4 * g + 3];
                float h[4];
                if (is_eq) {
                    const float a = fast_tanh(A0 + bias);
                    const float s = 1.f - a * a;
                    h[0] = a;
                    h[1] = s * A1;
                    h[2] = s * A2;
                    h[3] = fmaf(s, A3, -2.f * a * s * A2 * A2);
                } else {
                    h[0] = fast_tanh(A0 + bias);
                    h[1] = fast_tanh(A1 + bias);
                    h[2] = fast_tanh(A2 + bias);
                    h[3] = fast_tanh(A3 + bias);
                }
                #pragma unroll
                for (int c = 0; c < 4; ++c)
                    Hh[mrow0 + c][ncol] = (_Float16)h[c];
            }
        __syncthreads();
    }

    // ---- final layer (128 -> 1): thread t reduces k-quarter (t&3) of row t>>2
    {
        const float b4v = b4[0];
        const int m = tid >> 2;
        const int q = tid & 3;
        float dot = 0.f;
        #pragma unroll
        for (int g = 0; g < 4; ++g) {
            const int f = 32 * q + 8 * g;
            const half8 hh = *(const half8*)&Hh[m][f];
            const float4 wa = *(const float4*)&W4[f];
            const float4 wb = *(const float4*)&W4[f + 4];
            dot = fmaf((float)hh[0], wa.x, dot);
            dot = fmaf((float)hh[1], wa.y, dot);
            dot = fmaf((float)hh[2], wa.z, dot);
            dot = fmaf((float)hh[3], wa.w, dot);
            dot = fmaf((float)hh[4], wb.x, dot);
            dot = fmaf((float)hh[5], wb.y, dot);
            dot = fmaf((float)hh[6], wb.z, dot);
            dot = fmaf((float)hh[7], wb.w, dot);
        }
        dot += __shfl_xor(dot, 1);   // reduce across the 4 k-quarters
        dot += __shfl_xor(dot, 2);   // full row-dot at all 4 lanes of the row

        if (is_eq) {
            // wave w holds rows [16w,16w+16) = points [4w,4w+4); lane = 16p' + 4c + q
            const float uu   = __shfl(dot, (lane & 48) + 0)  + b4v;
            const float utv  = __shfl(dot, (lane & 48) + 4);
            const float uxv  = __shfl(dot, (lane & 48) + 8);
            const float uxxv = __shfl(dot, (lane & 48) + 12);
            if ((lane & 15) == 0)
                out[blk * 16 + 4 * w + (lane >> 4)] = fmaf(uu, uxv, utv) - NU_F * uxxv;
        } else {
            if (q == 0)
                out[131072 + (blk - 8192) * 64 + m] = dot + b4v;
        }
    }
}

extern "C" void kernel_launch(void* const* d_in, const int* in_sizes, int n_in,
                              void* d_out, int out_size, void* d_ws, size_t ws_size,
                              hipStream_t stream)
{
    const float* tx_eq   = (const float*)d_in[0];
    const float* tx_init = (const float*)d_in[1];
    const float* tx_bnd  = (const float*)d_in[2];
    const float* W0 = (const float*)d_in[3];
    const float* b0 = (const float*)d_in[4];
    const float* W1 = (const float*)d_in[5];
    const float* b1 = (const float*)d_in[6];
    const float* W2 = (const float*)d_in[7];
    const float* b2 = (const float*)d_in[8];
    const float* W3 = (const float*)d_in[9];
    const float* b3 = (const float*)d_in[10];
    const float* W4 = (const float*)d_in[11];
    const float* b4 = (const float*)d_in[12];
    float* out = (float*)d_out;
    _Float16* wt = (_Float16*)d_ws;   // needs 196608 B

    hipLaunchKernelGGL(prep_kernel, dim3(192), dim3(256), 0, stream, W1, W2, W3, wt);
    // 8192 eq blocks (16 pts) + 128 ib blocks (64 pts)
    hipLaunchKernelGGL(pinn_kernel, dim3(8320), dim3(256), 0, stream,
                       tx_eq, tx_init, tx_bnd, W0, b0, b1, b2, b3, W4, b4,
                       (const _Float16*)wt, out);
}

// Round 11
// 217.817 us; speedup vs baseline: 1.6073x; 1.0067x over previous
//
#include <hip/hip_runtime.h>
#include <math.h>

#define NU_F 0.0031830988618379067f
#define HS 136   // halves per H row: 17*8 -> 16B-aligned, odd 16B-stride = bank-balanced

typedef __attribute__((ext_vector_type(8))) _Float16 half8;
typedef __attribute__((ext_vector_type(4))) _Float16 half4;
typedef __attribute__((ext_vector_type(16))) float f32x16;

// tanh via exp2 + fast rcp: ~5 VALU (2 on trans pipe). inf-safe: e=inf -> 1, e=0 -> -1.
__device__ __forceinline__ float fast_tanh(float x) {
    const float e = __builtin_amdgcn_exp2f(x * 2.8853900817779268f);  // e^(2x)
    const float r = __builtin_amdgcn_rcpf(e + 1.f);
    return fmaf(-2.f, r, 1.f);
}

// ---------------------------------------------------------------------------
// Weight prep: W[l][k][n] fp32 -> k-tiled fp16 hi/lo:
//   idx = l*16384 + (k>>4)*2048 + n*16 + (k&15)
// so a wave's per-kt B-read (n-contiguous, 16 halves each) is one 1KB block.
// B keeps the hi+lo split (W at fp32 accuracy); A (activations) is fp16-only.
// ---------------------------------------------------------------------------
__global__ void prep_kernel(const float* __restrict__ W1,
                            const float* __restrict__ W2,
                            const float* __restrict__ W3,
                            _Float16* __restrict__ ws)
{
    const int g = blockIdx.x * 256 + threadIdx.x;   // 0..49151
    const int l = g >> 14;
    const int r = g & 16383;
    const int n = r & 127;
    const int k = r >> 7;
    const float* W = (l == 0) ? W1 : (l == 1) ? W2 : W3;
    const float w = W[k * 128 + n];
    const _Float16 hi = (_Float16)w;
    const _Float16 lo = (_Float16)(w - (float)hi);
    const int idx = l * 16384 + (k >> 4) * 2048 + n * 16 + (k & 15);
    ws[idx]         = hi;
    ws[49152 + idx] = lo;
}

// ---------------------------------------------------------------------------
// Blocks 0..8191: equation, 16 pts (M=64 rows, m = 4p + channel).
// Blocks 8192..8319: init/bound forward-only, 64 pts (m = p).
// Wave w computes cols [32w,32w+32) for all 64 rows (mt=0,1).
// Per (kt,mt): 2 MFMAs (ah*bl + ah*bh) -> W fp32-exact, activations fp16.
// Epilogue's tanh/chain-rule runs BEFORE the read barrier (registers only);
// only the LDS stores sit between the two barriers.
// ---------------------------------------------------------------------------
__launch_bounds__(256, 8)
__global__ void pinn_kernel(const float* __restrict__ tx_eq,
                            const float* __restrict__ tx_init,
                            const float* __restrict__ tx_bnd,
                            const float* __restrict__ W0, const float* __restrict__ b0,
                            const float* __restrict__ b1, const float* __restrict__ b2,
                            const float* __restrict__ b3,
                            const float* __restrict__ W4, const float* __restrict__ b4,
                            const _Float16* __restrict__ wt,
                            float* __restrict__ out)
{
    __shared__ _Float16 Hh[64][HS];   // 17.4 KB, in-place across layers

    const int tid   = threadIdx.x;
    const int blk   = blockIdx.x;
    const bool is_eq = (blk < 8192);
    const int w     = tid >> 6;
    const int lane  = tid & 63;
    const int col   = lane & 31;
    const int khalf = lane >> 5;
    const int ncol  = 32 * w + col;
    const int wofs  = ncol * 16 + khalf * 8;

    // ---- input layer (K=2, pointwise, fp32) ----
    if (is_eq) {
        const int p  = tid >> 4;                 // 0..15
        const int f0 = (tid & 15) * 8;
        const float tv = tx_eq[blk * 32 + 2 * p];
        const float xv = tx_eq[blk * 32 + 2 * p + 1];
        float vch[4][8];
        #pragma unroll
        for (int j = 0; j < 8; ++j) {
            const int f = f0 + j;
            const float w0v = W0[f];             // dz/dt
            const float w1v = W0[128 + f];       // dz/dx
            const float z = fmaf(tv, w0v, fmaf(xv, w1v, b0[f]));
            const float a = fast_tanh(z);
            const float s = 1.f - a * a;
            vch[0][j] = a;
            vch[1][j] = s * w0v;
            vch[2][j] = s * w1v;
            vch[3][j] = -2.f * a * s * w1v * w1v;
        }
        const int m0 = 4 * p;
        #pragma unroll
        for (int c = 0; c < 4; ++c) {
            half8 hh;
            #pragma unroll
            for (int j = 0; j < 8; ++j) hh[j] = (_Float16)vch[c][j];
            *(half8*)&Hh[m0 + c][f0] = hh;
        }
    } else {
        const int p  = tid >> 2;                 // 0..63 == row m
        const int f0 = (tid & 3) * 32;
        const int gp = (blk - 8192) * 64 + p;
        const float* src = (gp < 4096) ? tx_init : tx_bnd;
        const int idx = (gp < 4096) ? gp : gp - 4096;
        const float tv = src[2 * idx];
        const float xv = src[2 * idx + 1];
        #pragma unroll
        for (int g = 0; g < 4; ++g) {
            half8 hh;
            #pragma unroll
            for (int j = 0; j < 8; ++j) {
                const int f = f0 + 8 * g + j;
                hh[j] = (_Float16)fast_tanh(fmaf(tv, W0[f], fmaf(xv, W0[128 + f], b0[f])));
            }
            *(half8*)&Hh[p][f0 + 8 * g] = hh;
        }
    }
    __syncthreads();

    const float* barr[3] = {b1, b2, b3};

    #pragma unroll 1
    for (int layer = 0; layer < 3; ++layer) {
        const _Float16* __restrict__ ph = wt + layer * 16384 + wofs;
        const _Float16* __restrict__ pl = ph + 49152;
        const float bias = barr[layer][ncol];

        f32x16 acc[2];
        #pragma unroll
        for (int mt = 0; mt < 2; ++mt)
            #pragma unroll
            for (int e = 0; e < 16; ++e) acc[mt][e] = 0.f;

        // K-loop: rolling distance-2 B prefetch (each load = coalesced 1KB/wave)
        half8 bh[2], bl[2];
        bh[0] = *(const half8*)(ph);         bl[0] = *(const half8*)(pl);
        bh[1] = *(const half8*)(ph + 2048);  bl[1] = *(const half8*)(pl + 2048);

        #pragma unroll
        for (int kt = 0; kt < 8; ++kt) {
            half8 nbh, nbl;
            if (kt < 6) {
                nbh = *(const half8*)(ph + (kt + 2) * 2048);
                nbl = *(const half8*)(pl + (kt + 2) * 2048);
            }
            const int k0 = kt * 16 + khalf * 8;
            #pragma unroll
            for (int mt = 0; mt < 2; ++mt) {
                const half8 ah = *(const half8*)&Hh[mt * 32 + col][k0];
                acc[mt] = __builtin_amdgcn_mfma_f32_32x32x16_f16(ah, bl[kt & 1], acc[mt], 0, 0, 0);
                acc[mt] = __builtin_amdgcn_mfma_f32_32x32x16_f16(ah, bh[kt & 1], acc[mt], 0, 0, 0);
            }
            if (kt < 6) { bh[kt & 1] = nbh; bl[kt & 1] = nbl; }
        }

        // epilogue COMPUTE (registers only, before the barrier: overlaps other
        // waves' K-loops). reg group 4g..4g+3 = rows mt*32+8g+4khalf+{0..3};
        // eq: rows = {u,ut,ux,uxx} of one point -> chain rule in registers.
        half4 h16[2][4];
        #pragma unroll
        for (int mt = 0; mt < 2; ++mt)
            #pragma unroll
            for (int g = 0; g < 4; ++g) {
                const float A0 = acc[mt][4 * g + 0];
                const float A1 = acc[mt][4 * g + 1];
                const float A2 = acc[mt][4 * g + 2];
                const float A3 = acc[mt][4 * g + 3];
                half4 hv;
                if (is_eq) {
                    const float a = fast_tanh(A0 + bias);
                    const float s = 1.f - a * a;
                    hv[0] = (_Float16)a;
                    hv[1] = (_Float16)(s * A1);
                    hv[2] = (_Float16)(s * A2);
                    hv[3] = (_Float16)fmaf(s, A3, -2.f * a * s * A2 * A2);
                } else {
                    hv[0] = (_Float16)fast_tanh(A0 + bias);
                    hv[1] = (_Float16)fast_tanh(A1 + bias);
                    hv[2] = (_Float16)fast_tanh(A2 + bias);
                    hv[3] = (_Float16)fast_tanh(A3 + bias);
                }
                h16[mt][g] = hv;
            }

        __syncthreads();   // all reads of H done -> in-place overwrite safe

        // epilogue STORE (the only work between the two barriers)
        #pragma unroll
        for (int mt = 0; mt < 2; ++mt)
            #pragma unroll
            for (int g = 0; g < 4; ++g) {
                const int mrow0 = mt * 32 + 8 * g + 4 * khalf;
                Hh[mrow0 + 0][ncol] = h16[mt][g][0];
                Hh[mrow0 + 1][ncol] = h16[mt][g][1];
                Hh[mrow0 + 2][ncol] = h16[mt][g][2];
                Hh[mrow0 + 3][ncol] = h16[mt][g][3];
            }
        __syncthreads();
    }

    // ---- final layer (128 -> 1): thread t reduces k-quarter (t&3) of row t>>2
    {
        const float b4v = b4[0];
        const int m = tid >> 2;
        const int q = tid & 3;
        float dot = 0.f;
        #pragma unroll
        for (int g = 0; g < 4; ++g) {
            const int f = 32 * q + 8 * g;
            const half8 hh = *(const half8*)&Hh[m][f];
            const float4 wa = *(const float4*)&W4[f];
            const float4 wb = *(const float4*)&W4[f + 4];
            dot = fmaf((float)hh[0], wa.x, dot);
            dot = fmaf((float)hh[1], wa.y, dot);
            dot = fmaf((float)hh[2], wa.z, dot);
            dot = fmaf((float)hh[3], wa.w, dot);
            dot = fmaf((float)hh[4], wb.x, dot);
            dot = fmaf((float)hh[5], wb.y, dot);
            dot = fmaf((float)hh[6], wb.z, dot);
            dot = fmaf((float)hh[7], wb.w, dot);
        }
        dot += __shfl_xor(dot, 1);   // reduce across the 4 k-quarters
        dot += __shfl_xor(dot, 2);   // full row-dot at all 4 lanes of the row

        if (is_eq) {
            // wave w holds rows [16w,16w+16) = points [4w,4w+4); lane = 16p' + 4c + q
            const float uu   = __shfl(dot, (lane & 48) + 0)  + b4v;
            const float utv  = __shfl(dot, (lane & 48) + 4);
            const float uxv  = __shfl(dot, (lane & 48) + 8);
            const float uxxv = __shfl(dot, (lane & 48) + 12);
            if ((lane & 15) == 0)
                out[blk * 16 + 4 * w + (lane >> 4)] = fmaf(uu, uxv, utv) - NU_F * uxxv;
        } else {
            if (q == 0)
                out[131072 + (blk - 8192) * 64 + m] = dot + b4v;
        }
    }
}

extern "C" void kernel_launch(void* const* d_in, const int* in_sizes, int n_in,
                              void* d_out, int out_size, void* d_ws, size_t ws_size,
                              hipStream_t stream)
{
    const float* tx_eq   = (const float*)d_in[0];
    const float* tx_init = (const float*)d_in[1];
    const float* tx_bnd  = (const float*)d_in[2];
    const float* W0 = (const float*)d_in[3];
    const float* b0 = (const float*)d_in[4];
    const float* W1 = (const float*)d_in[5];
    const float* b1 = (const float*)d_in[6];
    const float* W2 = (const float*)d_in[7];
    const float* b2 = (const float*)d_in[8];
    const float* W3 = (const float*)d_in[9];
    const float* b3 = (const float*)d_in[10];
    const float* W4 = (const float*)d_in[11];
    const float* b4 = (const float*)d_in[12];
    float* out = (float*)d_out;
    _Float16* wt = (_Float16*)d_ws;   // needs 196608 B

    hipLaunchKernelGGL(prep_kernel, dim3(192), dim3(256), 0, stream, W1, W2, W3, wt);
    // 8192 eq blocks (16 pts) + 128 ib blocks (64 pts)
    hipLaunchKernelGGL(pinn_kernel, dim3(8320), dim3(256), 0, stream,
                       tx_eq, tx_init, tx_bnd, W0, b0, b1, b2, b3, W4, b4,
                       (const _Float16*)wt, out);
}

// Round 12
// 171.202 us; speedup vs baseline: 2.0449x; 1.2723x over previous
//
#include <hip/hip_runtime.h>
#include <math.h>

#define NU_F 0.0031830988618379067f
#define HS 136   // halves per H row: 17*8 -> 16B-aligned, odd 16B-stride = bank-balanced

typedef __attribute__((ext_vector_type(8))) _Float16 half8;
typedef __attribute__((ext_vector_type(4))) _Float16 half4;
typedef __attribute__((ext_vector_type(16))) float f32x16;

// tanh via exp2 + fast rcp: ~5 VALU (2 on trans pipe). inf-safe: e=inf -> 1, e=0 -> -1.
__device__ __forceinline__ float fast_tanh(float x) {
    const float e = __builtin_amdgcn_exp2f(x * 2.8853900817779268f);  // e^(2x)
    const float r = __builtin_amdgcn_rcpf(e + 1.f);
    return fmaf(-2.f, r, 1.f);
}

// ---------------------------------------------------------------------------
// Weight prep: W[l][k][n] fp32 -> k-tiled fp16 (hi only):
//   idx = l*16384 + (k>>4)*2048 + n*16 + (k&15)
// A wave's per-kt B-read (16 halves/lane, n-contiguous) is one 1KB block.
// ---------------------------------------------------------------------------
__global__ void prep_kernel(const float* __restrict__ W1,
                            const float* __restrict__ W2,
                            const float* __restrict__ W3,
                            _Float16* __restrict__ ws)
{
    const int g = blockIdx.x * 256 + threadIdx.x;   // 0..49151
    const int l = g >> 14;
    const int r = g & 16383;
    const int n = r & 127;
    const int k = r >> 7;
    const float* W = (l == 0) ? W1 : (l == 1) ? W2 : W3;
    const float w = W[k * 128 + n];
    ws[l * 16384 + (k >> 4) * 2048 + n * 16 + (k & 15)] = (_Float16)w;
}

// ---------------------------------------------------------------------------
// Blocks 0..8191: equation, 16 pts (M=64 rows, m = 4p + channel).
// Blocks 8192..8319: init/bound forward-only, 64 pts (m = p).
// Wave w computes cols [32w,32w+32) for all 64 rows (mt=0,1).
// W is fp16 (single MFMA per kt,mt); the ENTIRE layer's B sits in 8 named
// half8 registers, loaded back-to-back at layer start -> one vmcnt drain per
// layer instead of a per-kt L2 round trip.
// ---------------------------------------------------------------------------
__launch_bounds__(256, 6)
__global__ void pinn_kernel(const float* __restrict__ tx_eq,
                            const float* __restrict__ tx_init,
                            const float* __restrict__ tx_bnd,
                            const float* __restrict__ W0, const float* __restrict__ b0,
                            const float* __restrict__ b1, const float* __restrict__ b2,
                            const float* __restrict__ b3,
                            const float* __restrict__ W4, const float* __restrict__ b4,
                            const _Float16* __restrict__ wt,
                            float* __restrict__ out)
{
    __shared__ _Float16 Hh[64][HS];   // 17.4 KB, in-place across layers

    const int tid   = threadIdx.x;
    const int blk   = blockIdx.x;
    const bool is_eq = (blk < 8192);
    const int w     = tid >> 6;
    const int lane  = tid & 63;
    const int col   = lane & 31;
    const int khalf = lane >> 5;
    const int ncol  = 32 * w + col;
    const int wofs  = ncol * 16 + khalf * 8;

    // ---- input layer (K=2, pointwise, fp32) ----
    if (is_eq) {
        const int p  = tid >> 4;                 // 0..15
        const int f0 = (tid & 15) * 8;
        const float tv = tx_eq[blk * 32 + 2 * p];
        const float xv = tx_eq[blk * 32 + 2 * p + 1];
        float vch[4][8];
        #pragma unroll
        for (int j = 0; j < 8; ++j) {
            const int f = f0 + j;
            const float w0v = W0[f];             // dz/dt
            const float w1v = W0[128 + f];       // dz/dx
            const float z = fmaf(tv, w0v, fmaf(xv, w1v, b0[f]));
            const float a = fast_tanh(z);
            const float s = 1.f - a * a;
            vch[0][j] = a;
            vch[1][j] = s * w0v;
            vch[2][j] = s * w1v;
            vch[3][j] = -2.f * a * s * w1v * w1v;
        }
        const int m0 = 4 * p;
        #pragma unroll
        for (int c = 0; c < 4; ++c) {
            half8 hh;
            #pragma unroll
            for (int j = 0; j < 8; ++j) hh[j] = (_Float16)vch[c][j];
            *(half8*)&Hh[m0 + c][f0] = hh;
        }
    } else {
        const int p  = tid >> 2;                 // 0..63 == row m
        const int f0 = (tid & 3) * 32;
        const int gp = (blk - 8192) * 64 + p;
        const float* src = (gp < 4096) ? tx_init : tx_bnd;
        const int idx = (gp < 4096) ? gp : gp - 4096;
        const float tv = src[2 * idx];
        const float xv = src[2 * idx + 1];
        #pragma unroll
        for (int g = 0; g < 4; ++g) {
            half8 hh;
            #pragma unroll
            for (int j = 0; j < 8; ++j) {
                const int f = f0 + 8 * g + j;
                hh[j] = (_Float16)fast_tanh(fmaf(tv, W0[f], fmaf(xv, W0[128 + f], b0[f])));
            }
            *(half8*)&Hh[p][f0 + 8 * g] = hh;
        }
    }
    __syncthreads();

    const float* barr[3] = {b1, b2, b3};

    #pragma unroll 1
    for (int layer = 0; layer < 3; ++layer) {
        const _Float16* __restrict__ ph = wt + layer * 16384 + wofs;
        const float bias = barr[layer][ncol];

        // whole layer's B in 8 named registers; loads issued back-to-back.
        half8 q0 = *(const half8*)(ph);
        half8 q1 = *(const half8*)(ph + 2048);
        half8 q2 = *(const half8*)(ph + 4096);
        half8 q3 = *(const half8*)(ph + 6144);
        half8 q4 = *(const half8*)(ph + 8192);
        half8 q5 = *(const half8*)(ph + 10240);
        half8 q6 = *(const half8*)(ph + 12288);
        half8 q7 = *(const half8*)(ph + 14336);

        f32x16 acc0, acc1;
        #pragma unroll
        for (int e = 0; e < 16; ++e) { acc0[e] = 0.f; acc1[e] = 0.f; }

#define KSTEP(KT, Q)                                                          \
        {                                                                     \
            const int k0 = KT * 16 + khalf * 8;                               \
            const half8 ah0 = *(const half8*)&Hh[col][k0];                    \
            const half8 ah1 = *(const half8*)&Hh[32 + col][k0];               \
            acc0 = __builtin_amdgcn_mfma_f32_32x32x16_f16(ah0, Q, acc0, 0, 0, 0); \
            acc1 = __builtin_amdgcn_mfma_f32_32x32x16_f16(ah1, Q, acc1, 0, 0, 0); \
        }
        KSTEP(0, q0) KSTEP(1, q1) KSTEP(2, q2) KSTEP(3, q3)
        KSTEP(4, q4) KSTEP(5, q5) KSTEP(6, q6) KSTEP(7, q7)
#undef KSTEP

        // epilogue COMPUTE (registers only, before the barrier). C-layout:
        // reg group 4g..4g+3 = rows mt*32+8g+4khalf+{0..3} = the 4 derivative
        // channels of one point (eq) -> chain rule in registers.
        half4 h16[2][4];
        #pragma unroll
        for (int mt = 0; mt < 2; ++mt)
            #pragma unroll
            for (int g = 0; g < 4; ++g) {
                const float A0 = (mt ? acc1 : acc0)[4 * g + 0];
                const float A1 = (mt ? acc1 : acc0)[4 * g + 1];
                const float A2 = (mt ? acc1 : acc0)[4 * g + 2];
                const float A3 = (mt ? acc1 : acc0)[4 * g + 3];
                half4 hv;
                if (is_eq) {
                    const float a = fast_tanh(A0 + bias);
                    const float s = 1.f - a * a;
                    hv[0] = (_Float16)a;
                    hv[1] = (_Float16)(s * A1);
                    hv[2] = (_Float16)(s * A2);
                    hv[3] = (_Float16)fmaf(s, A3, -2.f * a * s * A2 * A2);
                } else {
                    hv[0] = (_Float16)fast_tanh(A0 + bias);
                    hv[1] = (_Float16)fast_tanh(A1 + bias);
                    hv[2] = (_Float16)fast_tanh(A2 + bias);
                    hv[3] = (_Float16)fast_tanh(A3 + bias);
                }
                h16[mt][g] = hv;
            }

        __syncthreads();   // all reads of H done -> in-place overwrite safe

        // epilogue STORE (the only work between the two barriers)
        #pragma unroll
        for (int mt = 0; mt < 2; ++mt)
            #pragma unroll
            for (int g = 0; g < 4; ++g) {
                const int mrow0 = mt * 32 + 8 * g + 4 * khalf;
                Hh[mrow0 + 0][ncol] = h16[mt][g][0];
                Hh[mrow0 + 1][ncol] = h16[mt][g][1];
                Hh[mrow0 + 2][ncol] = h16[mt][g][2];
                Hh[mrow0 + 3][ncol] = h16[mt][g][3];
            }
        __syncthreads();
    }

    // ---- final layer (128 -> 1): thread t reduces k-quarter (t&3) of row t>>2
    {
        const float b4v = b4[0];
        const int m = tid >> 2;
        const int q = tid & 3;
        float dot = 0.f;
        #pragma unroll
        for (int g = 0; g < 4; ++g) {
            const int f = 32 * q + 8 * g;
            const half8 hh = *(const half8*)&Hh[m][f];
            const float4 wa = *(const float4*)&W4[f];
            const float4 wb = *(const float4*)&W4[f + 4];
            dot = fmaf((float)hh[0], wa.x, dot);
            dot = fmaf((float)hh[1], wa.y, dot);
            dot = fmaf((float)hh[2], wa.z, dot);
            dot = fmaf((float)hh[3], wa.w, dot);
            dot = fmaf((float)hh[4], wb.x, dot);
            dot = fmaf((float)hh[5], wb.y, dot);
            dot = fmaf((float)hh[6], wb.z, dot);
            dot = fmaf((float)hh[7], wb.w, dot);
        }
        dot += __shfl_xor(dot, 1);   // reduce across the 4 k-quarters
        dot += __shfl_xor(dot, 2);   // full row-dot at all 4 lanes of the row

        if (is_eq) {
            // wave w holds rows [16w,16w+16) = points [4w,4w+4); lane = 16p' + 4c + q
            const float uu   = __shfl(dot, (lane & 48) + 0)  + b4v;
            const float utv  = __shfl(dot, (lane & 48) + 4);
            const float uxv  = __shfl(dot, (lane & 48) + 8);
            const float uxxv = __shfl(dot, (lane & 48) + 12);
            if ((lane & 15) == 0)
                out[blk * 16 + 4 * w + (lane >> 4)] = fmaf(uu, uxv, utv) - NU_F * uxxv;
        } else {
            if (q == 0)
                out[131072 + (blk - 8192) * 64 + m] = dot + b4v;
        }
    }
}

extern "C" void kernel_launch(void* const* d_in, const int* in_sizes, int n_in,
                              void* d_out, int out_size, void* d_ws, size_t ws_size,
                              hipStream_t stream)
{
    const float* tx_eq   = (const float*)d_in[0];
    const float* tx_init = (const float*)d_in[1];
    const float* tx_bnd  = (const float*)d_in[2];
    const float* W0 = (const float*)d_in[3];
    const float* b0 = (const float*)d_in[4];
    const float* W1 = (const float*)d_in[5];
    const float* b1 = (const float*)d_in[6];
    const float* W2 = (const float*)d_in[7];
    const float* b2 = (const float*)d_in[8];
    const float* W3 = (const float*)d_in[9];
    const float* b3 = (const float*)d_in[10];
    const float* W4 = (const float*)d_in[11];
    const float* b4 = (const float*)d_in[12];
    float* out = (float*)d_out;
    _Float16* wt = (_Float16*)d_ws;   // needs 98304 B

    hipLaunchKernelGGL(prep_kernel, dim3(192), dim3(256), 0, stream, W1, W2, W3, wt);
    // 8192 eq blocks (16 pts) + 128 ib blocks (64 pts)
    hipLaunchKernelGGL(pinn_kernel, dim3(8320), dim3(256), 0, stream,
                       tx_eq, tx_init, tx_bnd, W0, b0, b1, b2, b3, W4, b4,
                       (const _Float16*)wt, out);
}